// Round 2
// baseline (86.271 us; speedup 1.0000x reference)
//
#include <hip/hip_runtime.h>
#include <math.h>

// 8 waves (512 threads) per batch element. State psi (4096 fp32) split:
//   flat bits [11:6] = lane id (qubits 0..5, qubit i <-> lane bit 5-i)
//   flat bits [5:3]  = wave id (q6=4, q7=2, q8=1)   <- LDS cross-wave (b128)
//   flat bits [2:0]  = reg  id (q9=bit2, q10=bit1, q11=bit0) <- in-register
//
// R8 (this version): ROLLED code. Theory: the fully-unrolled kernel body
// (~2800+ static VALU inst, stage loop unrolled by compiler => ~50 KB) blows
// the 32 KB I$ and the kernel is instruction-fetch-streaming bound -- which
// explains why R7's barrier elimination was a null (code size unchanged) and
// why measured time is ~4x the VALU-issue model. This version replaces the
// templated per-neuron instantiations with ONE runtime-mask neuron loop and
// rolls the unitary lane rotations (runtime __shfl_xor instead of
// compile-time DPP). ~6-8x smaller static code, ~+10% dynamic instructions.

typedef float v2f __attribute__((ext_vector_type(2)));

#define NSLOT 512  // 8 waves * 64 lanes

__device__ __forceinline__ v2f mk(float a, float b) { v2f r; r.x = a; r.y = b; return r; }

// native sincos: v_sin_f32/v_cos_f32 take revolutions (D = sin(S0*2pi)).
// |angle| here <= ~25 rad (~4 revolutions) -- well inside HW range.
__device__ __forceinline__ void fast_sincos(float a, float* s, float* c) {
    float r = a * 0.15915494309189535f;  // 1/(2*pi)
    *s = __builtin_amdgcn_sinf(r);
    *c = __builtin_amdgcn_cosf(r);
}

// runtime-mask lane rY on a lane-bit qubit (ds_bpermute path)
__device__ __forceinline__ void lane_ry_rt(v2f (&V)[4], float c, float s, int ln, int LM) {
    float ss = (ln & LM) ? s : -s;
#pragma unroll
    for (int k = 0; k < 4; ++k) {
        v2f p = mk(__shfl_xor(V[k].x, LM, 64), __shfl_xor(V[k].y, LM, 64));
        V[k] = c * V[k] + ss * p;
    }
}

// merged 3-qubit cross-wave rotation R(q6)*R(q7)*R(q8) (they commute).
// One full-state LDS write + ONE barrier + 8-point gather per thread.
__device__ __forceinline__ void wave_ry3(v2f (&V)[4],
                                         float c4, float s4,   // qubit 6 (mask 4)
                                         float c2, float s2,   // qubit 7 (mask 2)
                                         float c1, float s1,   // qubit 8 (mask 1)
                                         int wv, int ln, float4* buf) {
    const int slot = wv * 64 + ln;
    buf[slot]         = make_float4(V[0].x, V[0].y, V[1].x, V[1].y);
    buf[NSLOT + slot] = make_float4(V[2].x, V[2].y, V[3].x, V[3].y);

    // per-bit factors: A_b = (source bit p=0), B_b = (source bit p=1)
    const float A4 = (wv & 4) ? s4 : c4,  B4 = (wv & 4) ? c4 : -s4;
    const float A2 = (wv & 2) ? s2 : c2,  B2 = (wv & 2) ? c2 : -s2;
    const float A1 = (wv & 1) ? s1 : c1,  B1 = (wv & 1) ? c1 : -s1;

    __syncthreads();

    v2f a0 = mk(0.f, 0.f), a1 = a0, a2 = a0, a3 = a0;
#pragma unroll
    for (int pv = 0; pv < 8; ++pv) {
        const float k = ((pv & 4) ? B4 : A4) *
                        ((pv & 2) ? B2 : A2) *
                        ((pv & 1) ? B1 : A1);
        float4 t0 = buf[pv * 64 + ln];
        float4 t1 = buf[NSLOT + pv * 64 + ln];
        a0 += k * mk(t0.x, t0.y);
        a1 += k * mk(t0.z, t0.w);
        a2 += k * mk(t1.x, t1.y);
        a3 += k * mk(t1.z, t1.w);
    }
    V[0] = a0; V[1] = a1; V[2] = a2; V[3] = a3;
}

// First half of the neuron on one q9-group: RB(+), crY(pi,10,11), RB(-).
__device__ __forceinline__ void half1(v2f V0, v2f V1, float c, float s,
                                      v2f& u0, v2f& u1) {
    v2f t0 = c * V0 - s * V1;
    v2f t1 = s * V0 + c * V1;
    v2f t1s = __builtin_shufflevector(t1, t1, 1, 0);
    u0 =  c * t0 + mk(-s,  s) * t1s;
    u1 = -s * t0 + mk(-c,  c) * t1s;
}

// Second half: RB(+), crY(-pi,10,11), RB(-).
__device__ __forceinline__ void half2(v2f& V0, v2f& V1, float c, float s,
                                      v2f u0, v2f u1) {
    v2f r0 = c * u0 - s * u1;
    v2f r1 = s * u0 + c * u1;
    v2f r1s = __builtin_shufflevector(r1, r1, 1, 0);
    V0 =  c * r0 + mk( s, -s) * r1s;
    V1 = -s * r0 + mk( c, -c) * r1s;
}

__global__ __launch_bounds__(512, 4) void rvqe_kernel(
    const float* __restrict__ psi_in,   // (B, 4096)
    const int*   __restrict__ inp,      // (6,)
    const float* __restrict__ ut,       // (2, 10)
    const float* __restrict__ nt,       // (2, 10, 11)
    float* __restrict__ out_probs,      // (B, 64)
    float* __restrict__ out_psi)        // (B, 4096)
{
    __shared__ float4 xbuf[2][2 * NSLOT];  // 2 x 16 KB

    const int b   = blockIdx.x;
    const int tid = threadIdx.x;
    const int ln  = tid & 63;
    const int wv  = tid >> 6;   // bit2=q6, bit1=q7, bit0=q8
    int bi = 0;

    // BitFlip: fold X on input lanes into load address
    int flip = 0;
#pragma unroll
    for (int l = 0; l < 6; ++l)
        if (inp[l] == 1) flip |= 1 << (5 - l);

    v2f V[4];
    {
        const float* src = psi_in + (size_t)b * 4096 + (((ln ^ flip) & 63) << 6) + (wv << 3);
        float4 t0 = ((const float4*)src)[0];
        float4 t1 = ((const float4*)src)[1];
        V[0] = mk(t0.x, t0.y); V[1] = mk(t0.z, t0.w);
        V[2] = mk(t1.x, t1.y); V[3] = mk(t1.z, t1.w);
    }

#pragma unroll 1
    for (int s = 0; s < 2; ++s) {
        const float* uts = ut + s * 10;
        const float* nts = nt + (size_t)s * 110;

        // ---- UnitaryLayer: rY(uts[i]) on qubit i ----
        // qubits 0..5: lane-bit rotations, rolled with runtime mask
#pragma unroll 1
        for (int i = 0; i < 6; ++i) {
            float cc, ss;
            fast_sincos(0.5f * uts[i], &ss, &cc);
            lane_ry_rt(V, cc, ss, ln, 32 >> i);
        }
        // qubits 6,7,8: ONE merged cross-wave exchange
        {
            float c6, s6, c7, s7, c8, s8;
            fast_sincos(0.5f * uts[6], &s6, &c6);
            fast_sincos(0.5f * uts[7], &s7, &c7);
            fast_sincos(0.5f * uts[8], &s8, &c8);
            wave_ry3(V, c6, s6, c7, s7, c8, s8, wv, ln, xbuf[bi]); bi ^= 1;
        }
        // qubit 9 = reg-group bit: A<->B
        {
            float cc, ss;
            fast_sincos(0.5f * uts[9], &ss, &cc);
            v2f n0 = cc * V[0] - ss * V[2];
            v2f n2 = ss * V[0] + cc * V[2];
            v2f n1 = cc * V[1] - ss * V[3];
            v2f n3 = ss * V[1] + cc * V[3];
            V[0] = n0; V[1] = n1; V[2] = n2; V[3] = n3;
        }

        // ---- QuantumNeuronLayer: ONE rolled loop, uniform branches ----
#pragma unroll 1
        for (int out = 0; out < 10; ++out) {
            const float* th = nts + out * 11;
            // pull all thetas first so s_loads issue early
            const float t0 = th[0], t1 = th[1], t2 = th[2], t3 = th[3];
            const float t4 = th[4], t5 = th[5], t6 = th[6], t7 = th[7];
            const float t8 = th[8], t9 = th[9], t10 = th[10];

            float a0 = (ln & 32) ? t0 : 0.f;
            float a1 = (ln & 16) ? t1 : 0.f;
            float a2 = (ln &  8) ? t2 : 0.f;
            float a3 = (ln &  4) ? t3 : 0.f;
            float a4 = (ln &  2) ? t4 : 0.f;
            float a5 = (ln &  1) ? t5 : 0.f;
            float wsum = t10;
            if (wv & 4) wsum += t6;   // wv uniform per wave -> SALU select
            if (wv & 2) wsum += t7;
            if (wv & 1) wsum += t8;
            float phih = 0.5f * (((a0 + a1) + (a2 + a3)) + ((a4 + a5) + wsum));

            float sA, cA, sB, cB;
            fast_sincos(phih, &sA, &cA);
            fast_sincos(phih + 0.5f * t9, &sB, &cB);

            v2f uA0, uA1, uB0, uB1;
            half1(V[0], V[1], cA, sA, uA0, uA1);
            half1(V[2], V[3], cB, sB, uB0, uB1);

            // T = crY(pi, ctrl q11, tgt out) on the q11=1 (.y) components
            if (out < 6) {                 // lane-bit target
                const int LM = 32 >> out;
                float ssn = (ln & LM) ? 1.f : -1.f;
                uA0.y = ssn * __shfl_xor(uA0.y, LM, 64);
                uA1.y = ssn * __shfl_xor(uA1.y, LM, 64);
                uB0.y = ssn * __shfl_xor(uB0.y, LM, 64);
                uB1.y = ssn * __shfl_xor(uB1.y, LM, 64);
            } else if (out < 9) {          // wave-bit target: LDS exchange
                const int WM = 1 << (8 - out);
                float4* buf = xbuf[bi]; bi ^= 1;
                const int slot = wv * 64 + ln;
                buf[slot] = make_float4(uA0.y, uA1.y, uB0.y, uB1.y);
                __syncthreads();
                const int pslot = (wv ^ WM) * 64 + ln;
                float ssn = (wv & WM) ? 1.f : -1.f;
                float4 t = buf[pslot];
                uA0.y = ssn * t.x; uA1.y = ssn * t.y;
                uB0.y = ssn * t.z; uB1.y = ssn * t.w;
            } else {                       // out == 9: reg-group bit
                float x1 = uA0.y, x3 = uA1.y;
                uA0.y = -uB0.y; uA1.y = -uB1.y;
                uB0.y = x1;     uB1.y = x3;
            }

            half2(V[0], V[1], cA, sA, uA0, uA1);
            half2(V[2], V[3], cB, sB, uB0, uB1);
        }
    }

    // ---- probs: marginal |amp|^2 over qubits 6..11 (wave + reg bits) ----
    float acc = 0.f;
#pragma unroll
    for (int k = 0; k < 4; ++k) acc += V[k].x * V[k].x + V[k].y * V[k].y;
    {
        float* pb = (float*)&xbuf[bi][0];  // dbuf invariant: safe to write pre-barrier
        pb[wv * 64 + ln] = acc;
        __syncthreads();
        if (wv == 0) {
            float t = 0.f;
#pragma unroll
            for (int w = 0; w < 8; ++w) t += pb[w * 64 + ln];
            out_probs[(size_t)b * 64 + ln] = t;
        }
    }

    // ---- write final psi ----
    float* dst = out_psi + (size_t)b * 4096 + (ln << 6) + (wv << 3);
    ((float4*)dst)[0] = make_float4(V[0].x, V[0].y, V[1].x, V[1].y);
    ((float4*)dst)[1] = make_float4(V[2].x, V[2].y, V[3].x, V[3].y);
}

extern "C" void kernel_launch(void* const* d_in, const int* in_sizes, int n_in,
                              void* d_out, int out_size, void* d_ws, size_t ws_size,
                              hipStream_t stream) {
    const float* psi = (const float*)d_in[0];
    const int*   inp = (const int*)d_in[1];
    const float* ut  = (const float*)d_in[2];
    const float* nt  = (const float*)d_in[3];

    const int B = in_sizes[0] >> 12;          // 4096 amplitudes per state
    float* probs = (float*)d_out;             // (B, 64) first
    float* opsi  = probs + (size_t)B * 64;    // then (B, 4096)

    rvqe_kernel<<<B, 512, 0, stream>>>(psi, inp, ut, nt, probs, opsi);
}